// Round 2
// baseline (3019.564 us; speedup 1.0000x reference)
//
#include <hip/hip_runtime.h>

typedef unsigned int u32;
typedef unsigned long long u64;

#define SORT_N 65536u

// ctrl u32 offsets (separate cache lines for read vs atomic counters)
#define C_PT    0    // pre-threshold coarse bin
#define C_NC    16   // candidate count (atomic)
#define C_T     32   // exact 31-bit threshold
#define C_CUT   33   // tie index cutoff
#define C_NM    48   // member count (atomic)

__device__ __forceinline__ u32 fkey32(u32 fb) {
  return (fb & 0x80000000u) ? ~fb : (fb | 0x80000000u);
}

__device__ __forceinline__ u32 lane_id() {
  return __builtin_amdgcn_mbcnt_hi(~0u, __builtin_amdgcn_mbcnt_lo(~0u, 0u));
}

// wave-aggregated append: one atomic per wave; returns slot (pred lanes) else ~0u
__device__ __forceinline__ u32 wave_append(u32* ctr, bool pred) {
  u64 mask = __ballot(pred);
  if (mask == 0ull) return 0xffffffffu;
  u32 lane = lane_id();
  u32 slot = 0xffffffffu;
  if (pred) {
    u32 rank = (u32)__popcll(mask & ((1ull << lane) - 1ull));
    int leader = __ffsll((unsigned long long)mask) - 1;
    u32 base = 0;
    if ((int)lane == leader) base = atomicAdd(ctr, (u32)__popcll(mask));
    base = (u32)__shfl((int)base, leader, 64);
    slot = base + rank;
  }
  return slot;
}

// ---------------- Sampled coarse histogram (1/32 of data, coalesced chunks) --------
__global__ void __launch_bounds__(256) k_sample(const float4* __restrict__ g,
                                                const float4* __restrict__ r,
                                                u32* __restrict__ shist, int n4) {
  __shared__ u32 lh[2048];
  for (int i = threadIdx.x; i < 2048; i += 256) lh[i] = 0;
  __syncthreads();
  u32 base = blockIdx.x * 32768u;  // sample first 1024 float4 of each 32768-chunk
#pragma unroll
  for (int j = 0; j < 4; j++) {
    u32 i = base + threadIdx.x + (u32)j * 256u;
    if ((int)i < n4) {
      float4 a = g[i]; float4 b = r[i];
      atomicAdd(&lh[(__float_as_uint(a.x + b.x) & 0x7fffffffu) >> 20], 1u);
      atomicAdd(&lh[(__float_as_uint(a.y + b.y) & 0x7fffffffu) >> 20], 1u);
      atomicAdd(&lh[(__float_as_uint(a.z + b.z) & 0x7fffffffu) >> 20], 1u);
      atomicAdd(&lh[(__float_as_uint(a.w + b.w) & 0x7fffffffu) >> 20], 1u);
    }
  }
  __syncthreads();
  for (int i = threadIdx.x; i < 2048; i += 256)
    if (lh[i]) atomicAdd(&shist[i], lh[i]);
}

// ---------------- Pick conservative pre-threshold bin from sample ----------
__global__ void __launch_bounds__(1024) k_pick(const u32* __restrict__ shist,
                                               u32* __restrict__ ctrl, u32 target) {
  __shared__ u32 b0[2048], b1[2048];
  u32 t = threadIdx.x;
  b0[t] = shist[t]; b0[t + 1024] = shist[t + 1024];
  __syncthreads();
  u32* src = b0; u32* dst = b1;
  for (u32 off = 1; off < 2048; off <<= 1) {
    for (u32 i = t; i < 2048; i += 1024) {
      u32 v = src[i];
      if (i + off < 2048) v += src[i + off];
      dst[i] = v;
    }
    __syncthreads();
    u32* tmp = src; src = dst; dst = tmp;
  }
  for (u32 i = t; i < 2048; i += 1024) {
    u32 cum = src[i];
    u32 nxt = (i + 1 < 2048) ? src[i + 1] : 0u;
    if (cum >= target && nxt < target) ctrl[C_PT] = i;
  }
}

// ---------------- THE big pass: flat, 1 float4/thread, res write + compact ----------
__global__ void __launch_bounds__(256) k_main1(const float4* __restrict__ g,
                                               const float4* __restrict__ r,
                                               const float* __restrict__ momp,
                                               float4* __restrict__ res4,
                                               u32* __restrict__ ctrl,
                                               u64* __restrict__ cand, u32 cap, int n4) {
  int i = blockIdx.x * 256 + (int)threadIdx.x;
  if (i >= n4) return;
  float m = momp[0];
  u32 PT = ctrl[C_PT];
  float4 a = g[i];
  float4 b = r[i];
  float4 ro;
  ro.x = b.x + m * a.x; ro.y = b.y + m * a.y;
  ro.z = b.z + m * a.z; ro.w = b.w + m * a.w;
  res4[i] = ro;
  u32 base4 = (u32)i * 4u;
  float cv0 = a.x + b.x, cv1 = a.y + b.y, cv2 = a.z + b.z, cv3 = a.w + b.w;
#define COMPACT(CV, J) { \
    u32 cb = __float_as_uint(CV); \
    u32 u = cb & 0x7fffffffu; \
    bool pred = (u >> 20) >= PT; \
    u32 slot = wave_append(&ctrl[C_NC], pred); \
    if (pred && slot < cap) \
      cand[slot] = ((u64)u << 32) | (u64)((base4 + J) | (cb & 0x80000000u)); \
  }
  COMPACT(cv0, 0u)
  COMPACT(cv1, 1u)
  COMPACT(cv2, 2u)
  COMPACT(cv3, 3u)
#undef COMPACT
}

// ---------------- Exact 31-bit select over candidates (single block) ----------
__global__ void __launch_bounds__(1024) k_refine(u32* __restrict__ ctrl,
                                                 const u64* __restrict__ cand,
                                                 u32 cap, u32 K) {
  __shared__ u32 h[2048], h2[2048];
  __shared__ u32 res[8];
  __shared__ u32 tie[2048];
  __shared__ u32 nt;
  u32 t = threadIdx.x;
  u32 nc = ctrl[C_NC]; if (nc > cap) nc = cap;

  // ---- level 0: coarse 11-bit bins (u >> 20)
  h[t] = 0; h[t + 1024] = 0;
  if (t == 0) nt = 0;
  __syncthreads();
  for (u32 i = t; i < nc; i += 1024)
    atomicAdd(&h[(u32)(cand[i] >> 52)], 1u);
  __syncthreads();
  u32* src = h; u32* dst = h2;
  for (u32 off = 1; off < 2048; off <<= 1) {
    for (u32 i = t; i < 2048; i += 1024) {
      u32 v = src[i];
      if (i + off < 2048) v += src[i + off];
      dst[i] = v;
    }
    __syncthreads();
    u32* tmp = src; src = dst; dst = tmp;
  }
  for (u32 i = t; i < 2048; i += 1024) {
    u32 cum = src[i];
    u32 nxt = (i + 1 < 2048) ? src[i + 1] : 0u;
    if (cum >= K && nxt < K) { res[0] = i; res[1] = nxt; }
  }
  __syncthreads();
  u32 B0 = res[0];
  u32 r0 = K - res[1];
  __syncthreads();

  // ---- level 1: bits 19..10 among coarse bin == B0
  h[t] = 0;
  __syncthreads();
  for (u32 i = t; i < nc; i += 1024) {
    u32 u = (u32)(cand[i] >> 32);
    if ((u >> 20) == B0) atomicAdd(&h[(u >> 10) & 1023u], 1u);
  }
  __syncthreads();
  src = h; dst = h2;
  for (u32 off = 1; off < 1024; off <<= 1) {
    u32 v = src[t];
    if (t + off < 1024) v += src[t + off];
    dst[t] = v;
    __syncthreads();
    u32* tmp = src; src = dst; dst = tmp;
  }
  {
    u32 cum = src[t];
    u32 nxt = (t + 1 < 1024) ? src[t + 1] : 0u;
    if (cum >= r0 && nxt < r0) { res[2] = t; res[3] = nxt; }
  }
  __syncthreads();
  u32 B1 = res[2];
  u32 r1 = r0 - res[3];
  u32 hi21 = (B0 << 10) | B1;
  __syncthreads();

  // ---- level 2: bits 9..0 among top-21 bits == hi21
  h[t] = 0;
  __syncthreads();
  for (u32 i = t; i < nc; i += 1024) {
    u32 u = (u32)(cand[i] >> 32);
    if ((u >> 10) == hi21) atomicAdd(&h[u & 1023u], 1u);
  }
  __syncthreads();
  src = h; dst = h2;
  for (u32 off = 1; off < 1024; off <<= 1) {
    u32 v = src[t];
    if (t + off < 1024) v += src[t + off];
    dst[t] = v;
    __syncthreads();
    u32* tmp = src; src = dst; dst = tmp;
  }
  {
    u32 cum = src[t];
    u32 nxt = (t + 1 < 1024) ? src[t + 1] : 0u;
    if (cum >= r1 && nxt < r1) { res[4] = t; res[5] = nxt; }
  }
  __syncthreads();
  u32 B2 = res[4];
  u32 r2 = r1 - res[5];
  u32 T = (hi21 << 10) | B2;
  __syncthreads();

  // ---- tie resolution: r2-th smallest index among u == T
  for (u32 i = t; i < nc; i += 1024) {
    u64 e = cand[i];
    if ((u32)(e >> 32) == T) {
      u32 p = atomicAdd(&nt, 1u);
      if (p < 2048u) tie[p] = (u32)e & 0x7fffffffu;
    }
  }
  __syncthreads();
  u32 ntc = nt; if (ntc > 2048u) ntc = 2048u;
  for (u32 i = t; i < ntc; i += 1024) {
    u32 ti = tie[i];
    u32 rank = 0;
    for (u32 j = 0; j < ntc; j++) rank += (tie[j] < ti) ? 1u : 0u;
    if (rank == r2 - 1u) ctrl[C_CUT] = ti;
  }
  if (t == 0) ctrl[C_T] = T;
}

// ---------------- Patch chosen candidates into outputs + member list ----------
__global__ void __launch_bounds__(256) k_patch(u32* __restrict__ ctrl,
                                               const u64* __restrict__ cand, u32 cap,
                                               float* __restrict__ res_out,
                                               float* __restrict__ sp_out,
                                               u64* __restrict__ memb) {
  u32 nc = ctrl[C_NC]; if (nc > cap) nc = cap;
  u32 T = ctrl[C_T];
  u32 cut = ctrl[C_CUT];
  u32 total = gridDim.x * blockDim.x;
  u32 iters = (cap + total - 1u) / total;   // uniform trip count for ballot
  u32 i = blockIdx.x * blockDim.x + threadIdx.x;
  for (u32 it = 0; it < iters; it++, i += total) {
    bool chosen = false;
    u32 idx = 0, cb = 0;
    if (i < nc) {
      u64 e = cand[i];
      u32 u = (u32)(e >> 32);
      u32 low = (u32)e;
      idx = low & 0x7fffffffu;
      cb = u | (low & 0x80000000u);
      chosen = (u > T) || (u == T && idx <= cut);
    }
    u32 slot = wave_append(&ctrl[C_NM], chosen);
    if (chosen) {
      res_out[idx] = 0.f;
      sp_out[idx] = __uint_as_float(cb);
      memb[slot] = ((u64)fkey32(cb) << 32) | (u64)idx;  // slot < k <= 65536 by construction
    }
  }
}

// ---------------- Pad member list to SORT_N ----------
__global__ void k_pad(u64* __restrict__ memb, int k) {
  int i = blockIdx.x * blockDim.x + threadIdx.x;
  if (i >= k && i < (int)SORT_N) memb[i] = ~0ull;
}

// ---------------- Bitonic sort (ascending) on 65536 u64 keys ----------
__global__ void __launch_bounds__(1024) k_blocal(u64* __restrict__ d) {
  __shared__ u64 s[8192];
  u32 base = blockIdx.x * 8192u;
  for (u32 i = threadIdx.x; i < 8192u; i += blockDim.x) s[i] = d[base + i];
  __syncthreads();
  for (u32 kk = 2; kk <= 8192u; kk <<= 1) {
    for (u32 jj = kk >> 1; jj > 0; jj >>= 1) {
      for (u32 t = threadIdx.x; t < 4096u; t += blockDim.x) {
        u32 i = 2u * t - (t & (jj - 1u));
        u32 l = i + jj;
        u64 x = s[i], y = s[l];
        bool up = (((base + i) & kk) == 0u);
        bool sw = up ? (x > y) : (y > x);
        if (sw) { s[i] = y; s[l] = x; }
      }
      __syncthreads();
    }
  }
  for (u32 i = threadIdx.x; i < 8192u; i += blockDim.x) d[base + i] = s[i];
}

__global__ void __launch_bounds__(1024) k_bstep(u64* __restrict__ d, u32 kk, u32 jj) {
  u32 t = blockIdx.x * blockDim.x + threadIdx.x;
  u32 i = 2u * t - (t & (jj - 1u));
  u32 l = i + jj;
  u64 x = d[i], y = d[l];
  bool up = ((i & kk) == 0u);
  bool sw = up ? (x > y) : (y > x);
  if (sw) { d[i] = y; d[l] = x; }
}

__global__ void __launch_bounds__(1024) k_bmerge(u64* __restrict__ d, u32 kk) {
  __shared__ u64 s[8192];
  u32 base = blockIdx.x * 8192u;
  for (u32 i = threadIdx.x; i < 8192u; i += blockDim.x) s[i] = d[base + i];
  __syncthreads();
  for (u32 jj = 4096u; jj > 0; jj >>= 1) {
    for (u32 t = threadIdx.x; t < 4096u; t += blockDim.x) {
      u32 i = 2u * t - (t & (jj - 1u));
      u32 l = i + jj;
      u64 x = s[i], y = s[l];
      bool up = (((base + i) & kk) == 0u);
      bool sw = up ? (x > y) : (y > x);
      if (sw) { s[i] = y; s[l] = x; }
    }
    __syncthreads();
  }
  for (u32 i = threadIdx.x; i < 8192u; i += blockDim.x) d[base + i] = s[i];
}

// ---------------- Emit indices (as float) and values ----------
__global__ void k_write(const u64* __restrict__ memb, float* __restrict__ out, int k) {
  int i = blockIdx.x * blockDim.x + threadIdx.x;
  if (i >= k) return;
  u64 e = memb[i];
  u32 idx = (u32)e & 0x7fffffffu;
  u32 h = (u32)(e >> 32);
  u32 fb = (h & 0x80000000u) ? (h ^ 0x80000000u) : ~h;
  out[i] = (float)idx;
  out[k + i] = __uint_as_float(fb);
}

extern "C" void kernel_launch(void* const* d_in, const int* in_sizes, int n_in,
                              void* d_out, int out_size, void* d_ws, size_t ws_size,
                              hipStream_t stream) {
  const float* g   = (const float*)d_in[0];
  const float* r   = (const float*)d_in[1];
  const float* mom = (const float*)d_in[2];
  int n = in_sizes[0];
  int k = (out_size - 2 * n) / 2;
  int n4 = n / 4;

  float* out = (float*)d_out;
  float* res_out = out + 2 * (size_t)k;
  float* sp_out  = res_out + (size_t)n;

  unsigned char* ws = (unsigned char*)d_ws;
  u32* ctrl  = (u32*)ws;                       // [0, 1024): control words
  u32* shist = (u32*)(ws + 1024);              // [1024, 9216): sample histogram
  u64* memb  = (u64*)(ws + 16384);             // 512 KB member list
  size_t cand_off = 16384 + (size_t)SORT_N * 8;
  u64* cand  = (u64*)(ws + cand_off);

  u32 cap = 2097152u;
  if (ws_size < cand_off + (size_t)cap * 8)
    cap = (u32)((ws_size - cand_off) / 8);

  // sample target: expected full-data candidate count ~ min(4k, 0.6*cap)
  int nsc = n4 / 32768; if (nsc < 1) nsc = 1;
  double sampleN = (double)nsc * 1024.0 * 4.0;
  double want = 4.0 * (double)k;
  double capd = 0.6 * (double)cap;
  if (want > capd) want = capd;
  if (want < 1.5 * (double)k) want = 1.5 * (double)k;
  u32 target = (u32)(want * sampleN / (double)n) + 1u;

  hipMemsetAsync(ws, 0, 16384, stream);                       // ctrl + shist
  hipMemsetAsync(sp_out, 0, (size_t)n * sizeof(float), stream); // sparse zeros

  k_sample<<<nsc, 256, 0, stream>>>((const float4*)g, (const float4*)r, shist, n4);
  k_pick<<<1, 1024, 0, stream>>>(shist, ctrl, target);
  k_main1<<<(n4 + 255) / 256, 256, 0, stream>>>((const float4*)g, (const float4*)r, mom,
                                                (float4*)res_out, ctrl, cand, cap, n4);
  k_refine<<<1, 1024, 0, stream>>>(ctrl, cand, cap, (u32)k);
  k_patch<<<2048, 256, 0, stream>>>(ctrl, cand, cap, res_out, sp_out, memb);
  k_pad<<<SORT_N / 256, 256, 0, stream>>>(memb, k);

  k_blocal<<<SORT_N / 8192, 1024, 0, stream>>>(memb);
  for (u32 kk = 16384u; kk <= SORT_N; kk <<= 1) {
    for (u32 jj = kk >> 1; jj >= 8192u; jj >>= 1)
      k_bstep<<<SORT_N / 2048, 1024, 0, stream>>>(memb, kk, jj);
    k_bmerge<<<SORT_N / 8192, 1024, 0, stream>>>(memb, kk);
  }

  k_write<<<(SORT_N + 255) / 256, 256, 0, stream>>>(memb, out, k);
}

// Round 3
// 930.164 us; speedup vs baseline: 3.2463x; 3.2463x over previous
//
#include <hip/hip_runtime.h>

typedef unsigned int u32;
typedef unsigned long long u64;

// ctrl u32 offsets
#define C_PT    0    // pre-threshold coarse bin
#define C_NC    16   // candidate count (atomic, block-granular)
#define C_T     32   // exact 31-bit threshold
#define C_CUT   33   // tie index cutoff
#define C_NM    48   // member count (atomic, block-granular)

#define MAIN_R      16            // float4 per thread in k_main
#define MAIN_ELEMS  (256u * MAIN_R)
#define PATCH_CHUNK 2048u
#define RCHUNK      4096          // keys staged per rank block

__device__ __forceinline__ u32 fkey32(u32 fb) {
  return (fb & 0x80000000u) ? ~fb : (fb | 0x80000000u);
}

// ---------------- Sampled coarse histogram (1/32 of data) ----------
__global__ void __launch_bounds__(256) k_sample(const float4* __restrict__ g,
                                                const float4* __restrict__ r,
                                                u32* __restrict__ shist, int n4) {
  __shared__ u32 lh[2048];
  for (int i = threadIdx.x; i < 2048; i += 256) lh[i] = 0;
  __syncthreads();
  u32 base = blockIdx.x * 32768u;
#pragma unroll
  for (int j = 0; j < 4; j++) {
    u32 i = base + threadIdx.x + (u32)j * 256u;
    if ((int)i < n4) {
      float4 a = g[i]; float4 b = r[i];
      atomicAdd(&lh[(__float_as_uint(a.x + b.x) & 0x7fffffffu) >> 20], 1u);
      atomicAdd(&lh[(__float_as_uint(a.y + b.y) & 0x7fffffffu) >> 20], 1u);
      atomicAdd(&lh[(__float_as_uint(a.z + b.z) & 0x7fffffffu) >> 20], 1u);
      atomicAdd(&lh[(__float_as_uint(a.w + b.w) & 0x7fffffffu) >> 20], 1u);
    }
  }
  __syncthreads();
  for (int i = threadIdx.x; i < 2048; i += 256)
    if (lh[i]) atomicAdd(&shist[i], lh[i]);
}

// ---------------- Pick conservative pre-threshold bin ----------
__global__ void __launch_bounds__(1024) k_pick(const u32* __restrict__ shist,
                                               u32* __restrict__ ctrl, u32 target) {
  __shared__ u32 b0[2048], b1[2048];
  u32 t = threadIdx.x;
  b0[t] = shist[t]; b0[t + 1024] = shist[t + 1024];
  __syncthreads();
  u32* src = b0; u32* dst = b1;
  for (u32 off = 1; off < 2048; off <<= 1) {
    for (u32 i = t; i < 2048; i += 1024) {
      u32 v = src[i];
      if (i + off < 2048) v += src[i + off];
      dst[i] = v;
    }
    __syncthreads();
    u32* tmp = src; src = dst; dst = tmp;
  }
  for (u32 i = t; i < 2048; i += 1024) {
    u32 cum = src[i];
    u32 nxt = (i + 1 < 2048) ? src[i + 1] : 0u;
    if (cum >= target && nxt < target) ctrl[C_PT] = i;
  }
}

// ---------------- Big pass: stream res + block-aggregated candidate compaction -----
__global__ void __launch_bounds__(256) k_main(const float4* __restrict__ g,
                                              const float4* __restrict__ r,
                                              const float* __restrict__ momp,
                                              float4* __restrict__ res4,
                                              u32* __restrict__ ctrl,
                                              u64* __restrict__ cand, u32 cap, int n4) {
  __shared__ u64 st[2048];
  __shared__ u32 lcnt, lbase;
  if (threadIdx.x == 0) lcnt = 0;
  __syncthreads();
  float m = momp[0];
  u32 PT = ctrl[C_PT];
  u32 seg = blockIdx.x * MAIN_ELEMS;
#pragma unroll 4
  for (int j = 0; j < MAIN_R; j++) {
    u32 i = seg + (u32)j * 256u + threadIdx.x;
    if ((int)i < n4) {
      float4 a = g[i];
      float4 b = r[i];
      float4 ro;
      ro.x = b.x + m * a.x; ro.y = b.y + m * a.y;
      ro.z = b.z + m * a.z; ro.w = b.w + m * a.w;
      res4[i] = ro;
      u32 base4 = i * 4u;
      float c0 = a.x + b.x, c1 = a.y + b.y, c2 = a.z + b.z, c3 = a.w + b.w;
#define PUSH(CV, J) { u32 cb = __float_as_uint(CV); u32 u = cb & 0x7fffffffu; \
      if ((u >> 20) >= PT) { \
        u64 e = ((u64)u << 32) | (u64)((base4 + J) | (cb & 0x80000000u)); \
        u32 p = atomicAdd(&lcnt, 1u); \
        if (p < 2048u) st[p] = e; \
        else { u32 gs = atomicAdd(&ctrl[C_NC], 1u); if (gs < cap) cand[gs] = e; } } }
      PUSH(c0, 0u)
      PUSH(c1, 1u)
      PUSH(c2, 2u)
      PUSH(c3, 3u)
#undef PUSH
    }
  }
  __syncthreads();
  u32 cnt = lcnt; if (cnt > 2048u) cnt = 2048u;
  if (threadIdx.x == 0) lbase = atomicAdd(&ctrl[C_NC], cnt);
  __syncthreads();
  u32 lb = lbase;
  for (u32 p = threadIdx.x; p < cnt; p += 256u) {
    u32 s = lb + p;
    if (s < cap) cand[s] = st[p];
  }
}

// ---------------- Exact 31-bit select over candidates (single block) ----------
__global__ void __launch_bounds__(1024) k_refine(u32* __restrict__ ctrl,
                                                 const u64* __restrict__ cand,
                                                 u32 cap, u32 K) {
  __shared__ u32 h[2048], h2[2048];
  __shared__ u32 res[8];
  __shared__ u32 tie[2048];
  __shared__ u32 nt;
  u32 t = threadIdx.x;
  u32 nc = ctrl[C_NC]; if (nc > cap) nc = cap;

  // level 0: coarse 11-bit bins (u >> 20)
  h[t] = 0; h[t + 1024] = 0;
  if (t == 0) nt = 0;
  __syncthreads();
  for (u32 i = t; i < nc; i += 1024)
    atomicAdd(&h[(u32)(cand[i] >> 52)], 1u);
  __syncthreads();
  u32* src = h; u32* dst = h2;
  for (u32 off = 1; off < 2048; off <<= 1) {
    for (u32 i = t; i < 2048; i += 1024) {
      u32 v = src[i];
      if (i + off < 2048) v += src[i + off];
      dst[i] = v;
    }
    __syncthreads();
    u32* tmp = src; src = dst; dst = tmp;
  }
  for (u32 i = t; i < 2048; i += 1024) {
    u32 cum = src[i];
    u32 nxt = (i + 1 < 2048) ? src[i + 1] : 0u;
    if (cum >= K && nxt < K) { res[0] = i; res[1] = nxt; }
  }
  __syncthreads();
  u32 B0 = res[0];
  u32 r0 = K - res[1];
  __syncthreads();

  // level 1: bits 19..10 among coarse bin == B0
  h[t] = 0;
  __syncthreads();
  for (u32 i = t; i < nc; i += 1024) {
    u32 u = (u32)(cand[i] >> 32);
    if ((u >> 20) == B0) atomicAdd(&h[(u >> 10) & 1023u], 1u);
  }
  __syncthreads();
  src = h; dst = h2;
  for (u32 off = 1; off < 1024; off <<= 1) {
    u32 v = src[t];
    if (t + off < 1024) v += src[t + off];
    dst[t] = v;
    __syncthreads();
    u32* tmp = src; src = dst; dst = tmp;
  }
  {
    u32 cum = src[t];
    u32 nxt = (t + 1 < 1024) ? src[t + 1] : 0u;
    if (cum >= r0 && nxt < r0) { res[2] = t; res[3] = nxt; }
  }
  __syncthreads();
  u32 B1 = res[2];
  u32 r1 = r0 - res[3];
  u32 hi21 = (B0 << 10) | B1;
  __syncthreads();

  // level 2: bits 9..0 among top-21 bits == hi21
  h[t] = 0;
  __syncthreads();
  for (u32 i = t; i < nc; i += 1024) {
    u32 u = (u32)(cand[i] >> 32);
    if ((u >> 10) == hi21) atomicAdd(&h[u & 1023u], 1u);
  }
  __syncthreads();
  src = h; dst = h2;
  for (u32 off = 1; off < 1024; off <<= 1) {
    u32 v = src[t];
    if (t + off < 1024) v += src[t + off];
    dst[t] = v;
    __syncthreads();
    u32* tmp = src; src = dst; dst = tmp;
  }
  {
    u32 cum = src[t];
    u32 nxt = (t + 1 < 1024) ? src[t + 1] : 0u;
    if (cum >= r1 && nxt < r1) { res[4] = t; res[5] = nxt; }
  }
  __syncthreads();
  u32 B2 = res[4];
  u32 r2 = r1 - res[5];
  u32 T = (hi21 << 10) | B2;
  __syncthreads();

  // tie resolution: r2-th smallest index among u == T
  for (u32 i = t; i < nc; i += 1024) {
    u64 e = cand[i];
    if ((u32)(e >> 32) == T) {
      u32 p = atomicAdd(&nt, 1u);
      if (p < 2048u) tie[p] = (u32)e & 0x7fffffffu;
    }
  }
  __syncthreads();
  u32 ntc = nt; if (ntc > 2048u) ntc = 2048u;
  for (u32 i = t; i < ntc; i += 1024) {
    u32 ti = tie[i];
    u32 rank = 0;
    for (u32 j = 0; j < ntc; j++) rank += (tie[j] < ti) ? 1u : 0u;
    if (rank == r2 - 1u) ctrl[C_CUT] = ti;
  }
  if (t == 0) ctrl[C_T] = T;
}

// ---------------- Patch chosen candidates (block-aggregated member append) --------
__global__ void __launch_bounds__(256) k_patch(u32* __restrict__ ctrl,
                                               const u64* __restrict__ cand, u32 cap,
                                               float* __restrict__ res_out,
                                               float* __restrict__ sp_out,
                                               u64* __restrict__ memb) {
  __shared__ u64 st[PATCH_CHUNK];
  __shared__ u32 cnt, basep;
  u32 b0 = blockIdx.x * PATCH_CHUNK;
  u32 nc = ctrl[C_NC]; if (nc > cap) nc = cap;
  if (b0 >= nc) return;                    // uniform early-out, before any sync
  if (threadIdx.x == 0) cnt = 0;
  __syncthreads();
  u32 T = ctrl[C_T];
  u32 cut = ctrl[C_CUT];
  for (u32 j = threadIdx.x; j < PATCH_CHUNK; j += 256u) {
    u32 i = b0 + j;
    if (i < nc) {
      u64 e = cand[i];
      u32 u = (u32)(e >> 32);
      u32 low = (u32)e;
      u32 idx = low & 0x7fffffffu;
      bool chosen = (u > T) || (u == T && idx <= cut);
      if (chosen) {
        u32 cb = u | (low & 0x80000000u);
        res_out[idx] = 0.f;
        sp_out[idx] = __uint_as_float(cb);
        u32 p = atomicAdd(&cnt, 1u);
        st[p] = ((u64)fkey32(cb) << 32) | (u64)idx;
      }
    }
  }
  __syncthreads();
  if (threadIdx.x == 0) basep = atomicAdd(&ctrl[C_NM], cnt);
  __syncthreads();
  u32 bp = basep;
  for (u32 p = threadIdx.x; p < cnt; p += 256u)
    memb[bp + p] = st[p];
}

// ---------------- Rank pass: partial[ct][m] = #{j in chunk ct : key_j < key_m} -----
__global__ void __launch_bounds__(256) k_rank(const u64* __restrict__ memb,
                                              u32* __restrict__ partial,
                                              int k, int mpad) {
  __shared__ u64 s[RCHUNK];
  u32 cbase = blockIdx.y * RCHUNK;
  for (u32 j = threadIdx.x; j < RCHUNK; j += 256u) {
    u32 jj = cbase + j;
    s[j] = (jj < (u32)k) ? memb[jj] : ~0ull;
  }
  __syncthreads();
  u32 m0 = blockIdx.x * 1024u + threadIdx.x * 4u;
  u64 k0 = (m0 + 0 < (u32)k) ? memb[m0 + 0] : 0ull;
  u64 k1 = (m0 + 1 < (u32)k) ? memb[m0 + 1] : 0ull;
  u64 k2 = (m0 + 2 < (u32)k) ? memb[m0 + 2] : 0ull;
  u64 k3 = (m0 + 3 < (u32)k) ? memb[m0 + 3] : 0ull;
  u32 r0 = 0, r1 = 0, r2 = 0, r3 = 0;
  const ulonglong2* s2 = (const ulonglong2*)s;
#pragma unroll 4
  for (int j = 0; j < RCHUNK / 2; j++) {
    ulonglong2 kk = s2[j];
    r0 += (kk.x < k0) + (kk.y < k0);
    r1 += (kk.x < k1) + (kk.y < k1);
    r2 += (kk.x < k2) + (kk.y < k2);
    r3 += (kk.x < k3) + (kk.y < k3);
  }
  u32* row = partial + (size_t)blockIdx.y * (u32)mpad;
  if (m0 + 3 < (u32)k) {
    uint4 v; v.x = r0; v.y = r1; v.z = r2; v.w = r3;
    *(uint4*)(row + m0) = v;
  } else {
    if (m0 + 0 < (u32)k) row[m0 + 0] = r0;
    if (m0 + 1 < (u32)k) row[m0 + 1] = r1;
    if (m0 + 2 < (u32)k) row[m0 + 2] = r2;
    if (m0 + 3 < (u32)k) row[m0 + 3] = r3;
  }
}

// ---------------- Reduce partial ranks + emit outputs ----------
__global__ void __launch_bounds__(256) k_out(const u64* __restrict__ memb,
                                             const u32* __restrict__ partial,
                                             float* __restrict__ out,
                                             int k, int mpad, int ct) {
  int m = blockIdx.x * 256 + (int)threadIdx.x;
  if (m >= k) return;
  u32 rank = 0;
  for (int c = 0; c < ct; c++)
    rank += partial[(size_t)c * (u32)mpad + (u32)m];
  u64 e = memb[m];
  u32 idx = (u32)e & 0x7fffffffu;
  u32 h = (u32)(e >> 32);
  u32 fb = (h & 0x80000000u) ? (h ^ 0x80000000u) : ~h;
  out[rank] = (float)idx;
  out[k + rank] = __uint_as_float(fb);
}

extern "C" void kernel_launch(void* const* d_in, const int* in_sizes, int n_in,
                              void* d_out, int out_size, void* d_ws, size_t ws_size,
                              hipStream_t stream) {
  const float* g   = (const float*)d_in[0];
  const float* r   = (const float*)d_in[1];
  const float* mom = (const float*)d_in[2];
  int n = in_sizes[0];
  int k = (out_size - 2 * n) / 2;
  int n4 = n / 4;

  float* out = (float*)d_out;
  float* res_out = out + 2 * (size_t)k;
  float* sp_out  = res_out + (size_t)n;

  unsigned char* ws = (unsigned char*)d_ws;
  u32* ctrl    = (u32*)ws;                    // [0, 256)
  u32* shist   = (u32*)(ws + 1024);           // [1024, 9216)
  u64* memb    = (u64*)(ws + 16384);          // 512 KB member list
  u32* partial = (u32*)(ws + 1048576);        // up to 8 MB partial ranks
  size_t cand_off = 9437184;                  // 9 MB
  u64* cand    = (u64*)(ws + cand_off);

  u32 cap = 524288u;
  if (ws_size < cand_off + (size_t)cap * 8)
    cap = (u32)((ws_size - cand_off) / 8);

  // sample target: expected full-data candidate count ~ 3*k (clamped)
  int nsc = n4 / 32768; if (nsc < 1) nsc = 1;
  double sampleN = (double)nsc * 1024.0 * 4.0;
  double want = 3.0 * (double)k;
  double capd = 0.5 * (double)cap;
  if (want > capd) want = capd;
  if (want < 1.5 * (double)k) want = 1.5 * (double)k;
  u32 target = (u32)(want * sampleN / (double)n) + 1u;

  int mtiles = (k + 1023) / 1024;
  int mpad   = mtiles * 1024;
  int ct     = (k + RCHUNK - 1) / RCHUNK;

  hipMemsetAsync(ws, 0, 16384, stream);                          // ctrl + shist
  hipMemsetAsync(sp_out, 0, (size_t)n * sizeof(float), stream);  // sparse zeros

  k_sample<<<nsc, 256, 0, stream>>>((const float4*)g, (const float4*)r, shist, n4);
  k_pick<<<1, 1024, 0, stream>>>(shist, ctrl, target);
  k_main<<<(n4 + (int)MAIN_ELEMS - 1) / (int)MAIN_ELEMS, 256, 0, stream>>>(
      (const float4*)g, (const float4*)r, mom, (float4*)res_out, ctrl, cand, cap, n4);
  k_refine<<<1, 1024, 0, stream>>>(ctrl, cand, cap, (u32)k);
  k_patch<<<(int)((cap + PATCH_CHUNK - 1) / PATCH_CHUNK), 256, 0, stream>>>(
      ctrl, cand, cap, res_out, sp_out, memb);

  dim3 rg((u32)mtiles, (u32)ct);
  k_rank<<<rg, 256, 0, stream>>>(memb, partial, k, mpad);
  k_out<<<(k + 255) / 256, 256, 0, stream>>>(memb, partial, out, k, mpad, ct);
}